// Round 1
// baseline (357.157 us; speedup 1.0000x reference)
//
#include <hip/hip_runtime.h>

// Submanifold sparse 3D conv, k=3, pad=1, no bias.
// Grid: 41 x 1024 x 1024, N=300000 active sites, C_in=32, C_out=64, fp32.
//
// Plan:
//  1) hipMemsetAsync an 8 MB open-addressing hash table (u64 slots: val<<32|lin)
//  2) build_hash_kernel: one thread per point, atomicCAS linear-probe insert
//  3) subm_conv_kernel: one wave64 per point, lane = output channel.
//     Lanes 0..26 do the 27 neighbor lookups in parallel; ballot+shfl iterate
//     the valid offsets; 32-FMA dot per offset with float4 feature loads and
//     coalesced weight reads.

#define ZD 41
#define YD 1024
#define XD 1024

constexpr int CIN = 32;
constexpr int COUT = 64;
constexpr unsigned HASH_BITS = 20;              // 2^20 slots, load factor ~0.29
constexpr unsigned CAP = 1u << HASH_BITS;
constexpr unsigned long long EMPTY = ~0ull;     // key=-1, val=-1 => empty

__device__ __forceinline__ unsigned hash_lin(unsigned lin) {
    return (lin * 2654435761u) >> (32 - HASH_BITS);
}

__global__ void build_hash_kernel(const int4* __restrict__ idx, int n,
                                  unsigned long long* __restrict__ table) {
    int i = blockIdx.x * blockDim.x + threadIdx.x;
    if (i >= n) return;
    int4 c = idx[i];                             // (b, z, y, x)
    unsigned lin = (unsigned)(c.y * (YD * XD) + c.z * XD + c.w);
    unsigned long long packed = ((unsigned long long)(unsigned)i << 32) | (unsigned long long)lin;
    unsigned h = hash_lin(lin);
    while (atomicCAS(&table[h], EMPTY, packed) != EMPTY) {
        h = (h + 1) & (CAP - 1);                 // coords are unique -> no dup check needed
    }
}

__device__ __forceinline__ int lookup(const unsigned long long* __restrict__ table,
                                      unsigned lin) {
    unsigned h = hash_lin(lin);
    while (true) {
        unsigned long long s = table[h];
        if (s == EMPTY) return -1;
        if ((unsigned)s == lin) return (int)(s >> 32);
        h = (h + 1) & (CAP - 1);
    }
}

__global__ __launch_bounds__(256) void subm_conv_kernel(
    const float* __restrict__ feat, const int4* __restrict__ idx,
    const float* __restrict__ weight, const unsigned long long* __restrict__ table,
    float* __restrict__ out, int n) {
    int wave = blockIdx.x * 4 + (threadIdx.x >> 6);
    int lane = threadIdx.x & 63;
    if (wave >= n) return;

    int4 c = idx[wave];

    // Lane-parallel neighbor lookup: lane l < 27 handles kernel offset l.
    int nidx = -1;
    if (lane < 27) {
        int dz = lane / 9 - 1;
        int dy = (lane / 3) % 3 - 1;
        int dx = lane % 3 - 1;
        int nz = c.y + dz, ny = c.z + dy, nx = c.w + dx;
        if ((unsigned)nz < (unsigned)ZD && (unsigned)ny < (unsigned)YD &&
            (unsigned)nx < (unsigned)XD) {
            nidx = lookup(table, (unsigned)(nz * (YD * XD) + ny * XD + nx));
        }
    }

    unsigned long long mask = __ballot(nidx >= 0);
    float a0 = 0.f, a1 = 0.f, a2 = 0.f, a3 = 0.f;

    while (mask) {
        int src = __ffsll((unsigned long long)mask) - 1;   // offset k == source lane
        mask &= mask - 1;
        int ni = __shfl(nidx, src);
        const float4* f4 = (const float4*)(feat + (long long)ni * CIN);
        const float* wk = weight + src * (CIN * COUT);
#pragma unroll
        for (int q = 0; q < 8; ++q) {
            float4 f = f4[q];                               // wave-uniform broadcast
            a0 = fmaf(f.x, wk[(4 * q + 0) * COUT + lane], a0);
            a1 = fmaf(f.y, wk[(4 * q + 1) * COUT + lane], a1);
            a2 = fmaf(f.z, wk[(4 * q + 2) * COUT + lane], a2);
            a3 = fmaf(f.w, wk[(4 * q + 3) * COUT + lane], a3);
        }
    }

    out[(long long)wave * COUT + lane] = (a0 + a1) + (a2 + a3);
}

extern "C" void kernel_launch(void* const* d_in, const int* in_sizes, int n_in,
                              void* d_out, int out_size, void* d_ws, size_t ws_size,
                              hipStream_t stream) {
    const float* feat   = (const float*)d_in[0];   // [N, 32]
    const int4*  idx    = (const int4*)d_in[1];    // [N, 4] int32
    const float* weight = (const float*)d_in[2];   // [27, 32, 64]
    float* out = (float*)d_out;                    // [N, 64]
    int n = in_sizes[0] / CIN;

    unsigned long long* table = (unsigned long long*)d_ws;   // 8 MB

    hipMemsetAsync(table, 0xFF, (size_t)CAP * sizeof(unsigned long long), stream);

    int bblocks = (n + 255) / 256;
    build_hash_kernel<<<bblocks, 256, 0, stream>>>(idx, n, table);

    int cblocks = (n + 3) / 4;                     // 4 waves (points) per block
    subm_conv_kernel<<<cblocks, 256, 0, stream>>>(feat, idx, weight, table, out, n);
}

// Round 2
// 338.641 us; speedup vs baseline: 1.0547x; 1.0547x over previous
//
#include <hip/hip_runtime.h>

// Submanifold sparse 3D conv, k=3, pad=1, no bias.
// Grid: 41 x 1024 x 1024, N=300000 active sites, C_in=32, C_out=64, fp32.
//
// R1 changes vs R0 (263 us conv, FETCH 333 MB, latency-bound):
//  - Octet-locality hash: slot = (hash(lin>>3)<<3) | (lin&7). The 3 x-adjacent
//    lookups of each (z,y) row share one 64B line -> ~11 lines/point vs 27.
//  - Center tap (offset 13) shortcut: nidx = self, no probe.
//  - 2 points per wave: lanes 0..26 probe point A, 32..58 probe point B;
//    fused accumulate loop (wave-uniform branch) doubles FMA/issue density
//    and overlaps the two lookup latency rounds.

#define ZD 41
#define YD 1024
#define XD 1024

constexpr int CIN = 32;
constexpr int COUT = 64;
constexpr unsigned HASH_BITS = 20;               // 2^20 slots, load ~0.29
constexpr unsigned CAP = 1u << HASH_BITS;
constexpr unsigned GROUP_BITS = HASH_BITS - 3;   // 2^17 octet groups
constexpr unsigned long long EMPTY = ~0ull;

__device__ __forceinline__ unsigned hash_slot(unsigned lin) {
    unsigned gh = ((lin >> 3) * 2654435761u) >> (32 - GROUP_BITS);
    return (gh << 3) | (lin & 7u);
}

__global__ void build_hash_kernel(const int4* __restrict__ idx, int n,
                                  unsigned long long* __restrict__ table) {
    int i = blockIdx.x * blockDim.x + threadIdx.x;
    if (i >= n) return;
    int4 c = idx[i];                             // (b, z, y, x)
    unsigned lin = (unsigned)(c.y * (YD * XD) + c.z * XD + c.w);
    unsigned long long packed = ((unsigned long long)(unsigned)i << 32) | (unsigned long long)lin;
    unsigned h = hash_slot(lin);
    while (atomicCAS(&table[h], EMPTY, packed) != EMPTY) {
        h = (h + 1) & (CAP - 1);                 // coords unique -> no dup check
    }
}

__device__ __forceinline__ int lookup(const unsigned long long* __restrict__ table,
                                      unsigned lin) {
    unsigned h = hash_slot(lin);
    while (true) {
        unsigned long long s = table[h];
        if (s == EMPTY) return -1;
        if ((unsigned)s == lin) return (int)(s >> 32);
        h = (h + 1) & (CAP - 1);
    }
}

__global__ __launch_bounds__(256) void subm_conv_kernel(
    const float* __restrict__ feat, const int4* __restrict__ idx,
    const float* __restrict__ weight, const unsigned long long* __restrict__ table,
    float* __restrict__ out, int n) {
    int wave = blockIdx.x * 4 + (threadIdx.x >> 6);
    int lane = threadIdx.x & 63;
    int p0 = wave * 2;
    int p1 = p0 + 1;
    if (p0 >= n) return;
    bool has_b = (p1 < n);

    int half = lane >> 5;                        // 0 = point A, 1 = point B
    int off  = lane & 31;                        // kernel offset within half
    int p = half ? (has_b ? p1 : p0) : p0;
    int4 c = idx[p];

    int nidx = -1;
    if (off < 27 && (half == 0 || has_b)) {
        if (off == 13) {
            nidx = p;                            // center tap: the point itself
        } else {
            int dz = off / 9 - 1;
            int dy = (off / 3) % 3 - 1;
            int dx = off % 3 - 1;
            int nz = c.y + dz, ny = c.z + dy, nx = c.w + dx;
            if ((unsigned)nz < (unsigned)ZD && (unsigned)ny < (unsigned)YD &&
                (unsigned)nx < (unsigned)XD) {
                nidx = lookup(table, (unsigned)(nz * (YD * XD) + ny * XD + nx));
            }
        }
    }

    unsigned long long mask = __ballot(nidx >= 0);
    float a0 = 0.f, a1 = 0.f, a2 = 0.f, a3 = 0.f;
    float b0 = 0.f, b1 = 0.f, b2 = 0.f, b3 = 0.f;

    while (mask) {
        int src = __ffsll((unsigned long long)mask) - 1;  // wave-uniform
        mask &= mask - 1;
        int ni = __shfl(nidx, src);
        int k = src & 31;                        // kernel offset id
        const float4* f4 = (const float4*)(feat + (long long)ni * CIN);
        const float* wk = weight + k * (CIN * COUT);
        if (src < 32) {                          // uniform branch: point A
#pragma unroll
            for (int q = 0; q < 8; ++q) {
                float4 f = f4[q];                // wave-uniform broadcast
                a0 = fmaf(f.x, wk[(4 * q + 0) * COUT + lane], a0);
                a1 = fmaf(f.y, wk[(4 * q + 1) * COUT + lane], a1);
                a2 = fmaf(f.z, wk[(4 * q + 2) * COUT + lane], a2);
                a3 = fmaf(f.w, wk[(4 * q + 3) * COUT + lane], a3);
            }
        } else {                                 // point B
#pragma unroll
            for (int q = 0; q < 8; ++q) {
                float4 f = f4[q];
                b0 = fmaf(f.x, wk[(4 * q + 0) * COUT + lane], b0);
                b1 = fmaf(f.y, wk[(4 * q + 1) * COUT + lane], b1);
                b2 = fmaf(f.z, wk[(4 * q + 2) * COUT + lane], b2);
                b3 = fmaf(f.w, wk[(4 * q + 3) * COUT + lane], b3);
            }
        }
    }

    out[(long long)p0 * COUT + lane] = (a0 + a1) + (a2 + a3);
    if (has_b) out[(long long)p1 * COUT + lane] = (b0 + b1) + (b2 + b3);
}

extern "C" void kernel_launch(void* const* d_in, const int* in_sizes, int n_in,
                              void* d_out, int out_size, void* d_ws, size_t ws_size,
                              hipStream_t stream) {
    const float* feat   = (const float*)d_in[0];   // [N, 32]
    const int4*  idx    = (const int4*)d_in[1];    // [N, 4] int32
    const float* weight = (const float*)d_in[2];   // [27, 32, 64]
    float* out = (float*)d_out;                    // [N, 64]
    int n = in_sizes[0] / CIN;

    unsigned long long* table = (unsigned long long*)d_ws;   // 8 MB

    hipMemsetAsync(table, 0xFF, (size_t)CAP * sizeof(unsigned long long), stream);

    int bblocks = (n + 255) / 256;
    build_hash_kernel<<<bblocks, 256, 0, stream>>>(idx, n, table);

    int waves = (n + 1) / 2;                       // 2 points per wave
    int cblocks = (waves + 3) / 4;                 // 4 waves per block
    subm_conv_kernel<<<cblocks, 256, 0, stream>>>(feat, idx, weight, table, out, n);
}